// Round 16
// baseline (778.022 us; speedup 1.0000x reference)
//
#include <hip/hip_runtime.h>
#include <hip/hip_bf16.h>

typedef __attribute__((ext_vector_type(8))) short short8;
typedef __attribute__((ext_vector_type(4))) float floatx4;
typedef unsigned short u16;

#define D 256
#define BM 64
#define NT 512
#define NBLK 512

__device__ __forceinline__ short f2bf(float f) {
    return __builtin_bit_cast(short, __float2bfloat16(f));
}

// prep: blocks [0,256): W1 fp32 [k][n] -> W1F bf16 MFMA-fragment-major:
// W1F[((k0t*16+nt)*64+lane)*8+j] = W1[k0t*32+(lane>>4)*8+j][nt*16+(lane&15)]
//       blocks [256,384): zero d_out.
__global__ void prep_kernel(const float* __restrict__ W1, u16* __restrict__ W1F,
                            float* __restrict__ out, int outn) {
    const int b = blockIdx.x;
    if (b < D) {
        const int k = b, n = threadIdx.x;
        const int k0t = k >> 5, g = (k >> 3) & 3, j = k & 7;
        const int nt = n >> 4, l15 = n & 15;
        W1F[(long)((((k0t << 4) + nt) << 6) + (g << 4) + l15) * 8 + j] = (u16)f2bf(W1[k * D + n]);
    } else {
        int i = (b - D) * 256 + threadIdx.x;
        const int stride = (gridDim.x - D) * 256;
        for (; i < outn; i += stride) out[i] = 0.f;
    }
}

// Producer/consumer specialized head. Persistent, 2 blocks/CU.
// Waves 0-3: stage A tile t+1 (reg burst -> cvt -> fragment-major LDS, dbuf).
// Waves 4-7: MFMA tile t (B from L2-resident W1F), silu-dot epilogue, s_red.
// One __syncthreads per phase (uniform); wave 4 scatters after the barrier.
// vmcnt domains are per-wave: consumer waits never drain the A-stream.
__launch_bounds__(NT, 4)
__global__ void head_kernel(const float* __restrict__ forces,
                            const float* __restrict__ V_st,
                            const u16*   __restrict__ W1F,
                            const float* __restrict__ b1,
                            const float* __restrict__ W2,
                            const float* __restrict__ b2,
                            const int*   __restrict__ idx_t,
                            float* __restrict__ out,
                            int E) {
    __shared__ u16 Abuf[2][32 * 512];   // 2 x 32 KiB bf16 A tiles, fragment-major
    __shared__ float s_red[2][2][BM];   // 1 KiB, phase-parity double-buffered

    const int tid  = threadIdx.x;
    const int lane = tid & 63;
    const int w    = tid >> 6;          // 0..7
    const int ntiles = E / BM;          // 12500 (E%64==0)
    const long b = blockIdx.x;
    const int niter = (int)((ntiles - b + NBLK - 1) / NBLK);

    // producer geometry: thread covers (arow=tid>>2, agg=tid&3), 8 chunks of 32B
    const int arow  = tid >> 2;         // 0..63 (producer tid range 0..255)
    const int agg   = tid & 3;
    const int art   = arow >> 4;
    const int aslot = ((agg << 4) | (arow & 15)) * 8;

    auto FILL = [&](int buf, long tile) {
        const float* abase = forces + (tile * BM + arow) * (long)D + agg * 8;
        floatx4 f0[8], f1[8];
#pragma unroll
        for (int k0t = 0; k0t < 8; ++k0t) {
            f0[k0t] = *(const floatx4*)(abase + k0t * 32);
            f1[k0t] = *(const floatx4*)(abase + k0t * 32 + 4);
        }
#pragma unroll
        for (int k0t = 0; k0t < 8; ++k0t) {
            short8 a;
#pragma unroll
            for (int j = 0; j < 4; ++j) { a[j] = f2bf(f0[k0t][j]); a[4 + j] = f2bf(f1[k0t][j]); }
            *(short8*)&Abuf[buf][(k0t * 4 + art) * 512 + aslot] = a;
        }
    };

    // consumer geometry
    const int cw  = w - 4;              // 0..3 (consumers)
    const int wm  = (cw >> 1) & 1;      // row half
    const int wn  = cw & 1;             // col half
    const int l15 = lane & 15;
    const int g   = lane >> 4;

    // ---- prologue: fill buf0 with tile b ----
    if (w < 4) FILL(0, b);
    __syncthreads();

    float vx = 0.f, vy = 0.f, vz = 0.f;
    int nd = 0;

    for (int i = 0; i < niter; ++i) {
        const int cur = i & 1;
        const long t = b + (long)i * NBLK;

        if (w < 4) {
            // ---------------- producer: stage tile t+NBLK into buf[cur^1] ----
            if (i + 1 < niter) FILL(cur ^ 1, t + NBLK);
        } else {
            // ---------------- consumer ----------------
            if (w == 4) {   // scatter-operand prefetch for tile t
                long e = t * BM + lane;
                vx = V_st[e * 3 + 0]; vy = V_st[e * 3 + 1]; vz = V_st[e * 3 + 2];
                nd = idx_t[e];
            }
            floatx4 acc[2][8];
#pragma unroll
            for (int mr = 0; mr < 2; ++mr)
#pragma unroll
                for (int nc = 0; nc < 8; ++nc)
                    acc[mr][nc] = (floatx4){0.f, 0.f, 0.f, 0.f};

#pragma unroll
            for (int k0t = 0; k0t < 8; ++k0t) {
                short8 af0 = *(const short8*)&Abuf[cur][(k0t * 4 + wm * 2 + 0) * 512 + lane * 8];
                short8 af1 = *(const short8*)&Abuf[cur][(k0t * 4 + wm * 2 + 1) * 512 + lane * 8];
#pragma unroll
                for (int nc = 0; nc < 8; ++nc) {
                    short8 bf = *(const short8*)(W1F +
                        (long)((k0t * 16 + wn * 8 + nc) * 64 + lane) * 8);
                    acc[0][nc] = __builtin_amdgcn_mfma_f32_16x16x32_bf16(af0, bf, acc[0][nc], 0, 0, 0);
                    acc[1][nc] = __builtin_amdgcn_mfma_f32_16x16x32_bf16(af1, bf, acc[1][nc], 0, 0, 0);
                }
            }

            // epilogue: silu(z+b1) dot W2 (b1/W2 loads L1-hot)
            float part[2][4];
#pragma unroll
            for (int mr = 0; mr < 2; ++mr)
#pragma unroll
                for (int rr = 0; rr < 4; ++rr) {
                    float sv = 0.f;
#pragma unroll
                    for (int nc = 0; nc < 8; ++nc) {
                        int n = wn * 128 + nc * 16 + l15;
                        float z = acc[mr][nc][rr] + b1[n];
                        float h = z / (1.f + __expf(-z));
                        sv += h * W2[n];
                    }
                    part[mr][rr] = sv;
                }
#pragma unroll
            for (int off = 1; off < 16; off <<= 1)
#pragma unroll
                for (int mr = 0; mr < 2; ++mr)
#pragma unroll
                    for (int rr = 0; rr < 4; ++rr)
                        part[mr][rr] += __shfl_xor(part[mr][rr], off, 16);
            if (l15 == 0) {
#pragma unroll
                for (int mr = 0; mr < 2; ++mr)
#pragma unroll
                    for (int rr = 0; rr < 4; ++rr)
                        s_red[cur][wn][wm * 32 + mr * 16 + g * 4 + rr] = part[mr][rr];
            }
        }

        __syncthreads();   // uniform: buf handoff + s_red[cur] ready

        if (w == 4) {      // scatter tile t; overlaps next phase's work
            float sv = s_red[cur][0][lane] + s_red[cur][1][lane] + b2[0];
            atomicAdd(&out[(long)nd * 3 + 0], sv * vx);
            atomicAdd(&out[(long)nd * 3 + 1], sv * vy);
            atomicAdd(&out[(long)nd * 3 + 2], sv * vz);
        }
    }
}

extern "C" void kernel_launch(void* const* d_in, const int* in_sizes, int n_in,
                              void* d_out, int out_size, void* d_ws, size_t ws_size,
                              hipStream_t stream) {
    const float* forces = (const float*)d_in[0];
    const float* V_st   = (const float*)d_in[1];
    const float* W1     = (const float*)d_in[2];
    const float* b1     = (const float*)d_in[3];
    const float* W2     = (const float*)d_in[4];
    const float* b2     = (const float*)d_in[5];
    const int*   idx    = (const int*)d_in[6];
    const int E = in_sizes[6];

    u16* W1F = (u16*)d_ws;  // 256*256*2 = 131072 B

    prep_kernel<<<D + 128, 256, 0, stream>>>(W1, W1F, (float*)d_out, out_size);
    head_kernel<<<NBLK, NT, 0, stream>>>(forces, V_st, W1F, b1, W2, b2, idx,
                                         (float*)d_out, E);
}

// Round 17
// 523.564 us; speedup vs baseline: 1.4860x; 1.4860x over previous
//
#include <hip/hip_runtime.h>
#include <hip/hip_bf16.h>

typedef __attribute__((ext_vector_type(8))) short short8;
typedef __attribute__((ext_vector_type(4))) float floatx4;
typedef unsigned short u16;

#define D 256
#define BM 64
#define NT 256

__device__ __forceinline__ short f2bf(float f) {
    return __builtin_bit_cast(short, __float2bfloat16(f));
}

// prep: blocks [0,256): W1 fp32 [k][n] -> W1F bf16 MFMA-fragment-major:
// W1F[((k0t*16+nt)*64+lane)*8+j] = W1[k0t*32+(lane>>4)*8+j][nt*16+(lane&15)]
//       blocks [256,384): zero d_out.
__global__ void prep_kernel(const float* __restrict__ W1, u16* __restrict__ W1F,
                            float* __restrict__ out, int outn) {
    const int b = blockIdx.x;
    if (b < D) {
        const int k = b, n = threadIdx.x;
        const int k0t = k >> 5, g = (k >> 3) & 3, j = k & 7;
        const int nt = n >> 4, l15 = n & 15;
        W1F[(long)((((k0t << 4) + nt) << 6) + (g << 4) + l15) * 8 + j] = (u16)f2bf(W1[k * D + n]);
    } else {
        int i = (b - D) * 256 + threadIdx.x;
        const int stride = (gridDim.x - D) * 256;
        for (; i < outn; i += stride) out[i] = 0.f;
    }
}

// Barrier-free dataflow head. Each wave independently owns 16 rows x 256 cols.
// KEY IDENTITY: with lane -> (row=l15, kchunk=g), the lane that loads
// A[row][g*8..g*8+8] IS the lane that consumes it as the MFMA A-fragment --
// the LDS round-trip of rounds 2-16 was a per-lane identity map, and the
// per-instruction global address set here is identical to the staged
// version's (16 rows x 4x16B, f0/f1 covering full 128B spans, MSHR-merged).
// No __shared__, no __syncthreads => NO forced vmcnt(0) anywhere: every wait
// is a compiler-counted dataflow wait, loads stay in flight across compute.
__launch_bounds__(NT, 2)
__global__ void head_kernel(const float* __restrict__ forces,
                            const float* __restrict__ V_st,
                            const u16*   __restrict__ W1F,
                            const float* __restrict__ b1,
                            const float* __restrict__ W2,
                            const float* __restrict__ b2,
                            const int*   __restrict__ idx_t,
                            float* __restrict__ out,
                            int E) {
    const int tid  = threadIdx.x;
    const int lane = tid & 63;
    const int w    = tid >> 6;        // 0..3: 16-row band within the block
    const int l15  = lane & 15;
    const int g    = lane >> 4;       // 0..3

    const long row0 = (long)blockIdx.x * BM + w * 16;   // E%64==0: no tail

    // ---- scatter-operand prefetch (oldest in the vmcnt stream, retires early)
    float vx[4], vy[4], vz[4];
    int nd[4] = {0, 0, 0, 0};
    if (l15 == 0) {
#pragma unroll
        for (int rr = 0; rr < 4; ++rr) {
            long e = row0 + g * 4 + rr;
            vx[rr] = V_st[e * 3 + 0];
            vy[rr] = V_st[e * 3 + 1];
            vz[rr] = V_st[e * 3 + 2];
            nd[rr] = idx_t[e];
        }
    }

    // ---- A burst: lane loads its OWN fragment data, 16 x 16B ----
    const float* abase = forces + (row0 + l15) * (long)D + g * 8;
    floatx4 f0[8], f1[8];
#pragma unroll
    for (int k0t = 0; k0t < 8; ++k0t) {
        f0[k0t] = *(const floatx4*)(abase + k0t * 32);
        f1[k0t] = *(const floatx4*)(abase + k0t * 32 + 4);
    }
    short8 af[8];
#pragma unroll
    for (int k0t = 0; k0t < 8; ++k0t) {
        short8 a;
#pragma unroll
        for (int j = 0; j < 4; ++j) { a[j] = f2bf(f0[k0t][j]); a[4 + j] = f2bf(f1[k0t][j]); }
        af[k0t] = a;
    }

    // ---- MFMA: 2 col-halves x 8 k-steps; B lane-contiguous from L2-hot W1F ----
    floatx4 acc[2][8];
#pragma unroll
    for (int h = 0; h < 2; ++h)
#pragma unroll
        for (int nc = 0; nc < 8; ++nc)
            acc[h][nc] = (floatx4){0.f, 0.f, 0.f, 0.f};

#pragma unroll
    for (int h = 0; h < 2; ++h)
#pragma unroll
        for (int k0t = 0; k0t < 8; ++k0t) {
            short8 bf[8];
#pragma unroll
            for (int nc = 0; nc < 8; ++nc)
                bf[nc] = *(const short8*)(W1F +
                    (long)((k0t * 16 + h * 8 + nc) * 64 + lane) * 8);
#pragma unroll
            for (int nc = 0; nc < 8; ++nc)
                acc[h][nc] = __builtin_amdgcn_mfma_f32_16x16x32_bf16(
                    af[k0t], bf[nc], acc[h][nc], 0, 0, 0);
        }

    // ---- epilogue: silu(z+b1) dot W2 over all 256 cols (b1/W2 L1-hot) ----
    float part[4] = {0.f, 0.f, 0.f, 0.f};   // C/D: col=l15, row=g*4+rr (m89)
#pragma unroll
    for (int h = 0; h < 2; ++h)
#pragma unroll
        for (int nc = 0; nc < 8; ++nc) {
            int n = h * 128 + nc * 16 + l15;
            float bb = b1[n], ww = W2[n];
#pragma unroll
            for (int rr = 0; rr < 4; ++rr) {
                float z = acc[h][nc][rr] + bb;
                float hs = z / (1.f + __expf(-z));
                part[rr] += hs * ww;
            }
        }

#pragma unroll
    for (int off = 1; off < 16; off <<= 1)
#pragma unroll
        for (int rr = 0; rr < 4; ++rr)
            part[rr] += __shfl_xor(part[rr], off, 16);

    // ---- scatter from owning lanes (row = g*4 + rr); fire-and-forget ----
    if (l15 == 0) {
        const float b2v = b2[0];
#pragma unroll
        for (int rr = 0; rr < 4; ++rr) {
            float sv = part[rr] + b2v;
            atomicAdd(&out[(long)nd[rr] * 3 + 0], sv * vx[rr]);
            atomicAdd(&out[(long)nd[rr] * 3 + 1], sv * vy[rr]);
            atomicAdd(&out[(long)nd[rr] * 3 + 2], sv * vz[rr]);
        }
    }
}

extern "C" void kernel_launch(void* const* d_in, const int* in_sizes, int n_in,
                              void* d_out, int out_size, void* d_ws, size_t ws_size,
                              hipStream_t stream) {
    const float* forces = (const float*)d_in[0];
    const float* V_st   = (const float*)d_in[1];
    const float* W1     = (const float*)d_in[2];
    const float* b1     = (const float*)d_in[3];
    const float* W2     = (const float*)d_in[4];
    const float* b2     = (const float*)d_in[5];
    const int*   idx    = (const int*)d_in[6];
    const int E = in_sizes[6];

    u16* W1F = (u16*)d_ws;  // 256*256*2 = 131072 B

    prep_kernel<<<D + 128, 256, 0, stream>>>(W1, W1F, (float*)d_out, out_size);
    const int grid = E / BM;
    head_kernel<<<grid, NT, 0, stream>>>(forces, V_st, W1F, b1, W2, b2, idx,
                                         (float*)d_out, E);
}

// Round 18
// 437.118 us; speedup vs baseline: 1.7799x; 1.1978x over previous
//
#include <hip/hip_runtime.h>
#include <hip/hip_bf16.h>

typedef __attribute__((ext_vector_type(8))) short short8;
typedef __attribute__((ext_vector_type(4))) float floatx4;
typedef unsigned short u16;

#define D 256
#define BM 64
#define NT 256

__device__ __forceinline__ short f2bf(float f) {
    return __builtin_bit_cast(short, __float2bfloat16(f));
}

// prep: blocks [0,256): W1 fp32 [k][n] -> W1F bf16 MFMA-fragment-major:
// W1F[((k0t*16+nt)*64+lane)*8+j] = W1[k0t*32+(lane>>4)*8+j][nt*16+(lane&15)]
//       blocks [256,384): zero d_out.
__global__ void prep_kernel(const float* __restrict__ W1, u16* __restrict__ W1F,
                            float* __restrict__ out, int outn) {
    const int b = blockIdx.x;
    if (b < D) {
        const int k = b, n = threadIdx.x;
        const int k0t = k >> 5, g = (k >> 3) & 3, j = k & 7;
        const int nt = n >> 4, l15 = n & 15;
        W1F[(long)((((k0t << 4) + nt) << 6) + (g << 4) + l15) * 8 + j] = (u16)f2bf(W1[k * D + n]);
    } else {
        int i = (b - D) * 256 + threadIdx.x;
        const int stride = (gridDim.x - D) * 256;
        for (; i < outn; i += stride) out[i] = 0.f;
    }
}

// Barrier-free dataflow head (R17) + SCHED FENCE forcing the A-burst.
// R17's failure: hipcc allocated 68 VGPR and sank each A-load next to its
// use -> serialized ~700cy waits, no MLP (VGPR_Count=68, HBM 11%). Fix:
// issue all 16 A-loads, then sched_barrier(0) -> loads cannot sink, 64
// dest VGPRs stay live, all 16 requests in flight. Still no LDS and no
// __syncthreads => no forced vmcnt(0) anywhere; every wait is counted.
__launch_bounds__(NT, 2)
__global__ void head_kernel(const float* __restrict__ forces,
                            const float* __restrict__ V_st,
                            const u16*   __restrict__ W1F,
                            const float* __restrict__ b1,
                            const float* __restrict__ W2,
                            const float* __restrict__ b2,
                            const int*   __restrict__ idx_t,
                            float* __restrict__ out,
                            int E) {
    const int tid  = threadIdx.x;
    const int lane = tid & 63;
    const int w    = tid >> 6;        // 0..3: 16-row band within the block
    const int l15  = lane & 15;
    const int g    = lane >> 4;       // 0..3

    const long row0 = (long)blockIdx.x * BM + w * 16;   // E%64==0: no tail

    // ---- scatter-operand prefetch (oldest in the vmcnt stream) ----
    float vx[4], vy[4], vz[4];
    int nd[4] = {0, 0, 0, 0};
    if (l15 == 0) {
#pragma unroll
        for (int rr = 0; rr < 4; ++rr) {
            long e = row0 + g * 4 + rr;
            vx[rr] = V_st[e * 3 + 0];
            vy[rr] = V_st[e * 3 + 1];
            vz[rr] = V_st[e * 3 + 2];
            nd[rr] = idx_t[e];
        }
    }

    // ---- A burst: lane loads its OWN fragment data, 16 x 16B, ALL in flight
    const float* abase = forces + (row0 + l15) * (long)D + g * 8;
    floatx4 f0[8], f1[8];
#pragma unroll
    for (int k0t = 0; k0t < 8; ++k0t) {
        f0[k0t] = *(const floatx4*)(abase + k0t * 32);
        f1[k0t] = *(const floatx4*)(abase + k0t * 32 + 4);
    }
    __builtin_amdgcn_sched_barrier(0);   // loads may not sink past this point

    short8 af[8];
#pragma unroll
    for (int k0t = 0; k0t < 8; ++k0t) {
        short8 a;
#pragma unroll
        for (int j = 0; j < 4; ++j) { a[j] = f2bf(f0[k0t][j]); a[4 + j] = f2bf(f1[k0t][j]); }
        af[k0t] = a;
    }

    // ---- MFMA: 2 col-halves x 8 k-steps; B lane-contiguous from L2-hot W1F ----
    floatx4 acc[2][8];
#pragma unroll
    for (int h = 0; h < 2; ++h)
#pragma unroll
        for (int nc = 0; nc < 8; ++nc)
            acc[h][nc] = (floatx4){0.f, 0.f, 0.f, 0.f};

#pragma unroll
    for (int h = 0; h < 2; ++h)
#pragma unroll
        for (int k0t = 0; k0t < 8; ++k0t) {
            short8 bf[8];
#pragma unroll
            for (int nc = 0; nc < 8; ++nc)
                bf[nc] = *(const short8*)(W1F +
                    (long)((k0t * 16 + h * 8 + nc) * 64 + lane) * 8);
#pragma unroll
            for (int nc = 0; nc < 8; ++nc)
                acc[h][nc] = __builtin_amdgcn_mfma_f32_16x16x32_bf16(
                    af[k0t], bf[nc], acc[h][nc], 0, 0, 0);
        }

    // ---- epilogue: silu(z+b1) dot W2 over all 256 cols (b1/W2 L1-hot) ----
    float part[4] = {0.f, 0.f, 0.f, 0.f};   // C/D: col=l15, row=g*4+rr (m89)
#pragma unroll
    for (int h = 0; h < 2; ++h)
#pragma unroll
        for (int nc = 0; nc < 8; ++nc) {
            int n = h * 128 + nc * 16 + l15;
            float bb = b1[n], ww = W2[n];
#pragma unroll
            for (int rr = 0; rr < 4; ++rr) {
                float z = acc[h][nc][rr] + bb;
                float hs = z / (1.f + __expf(-z));
                part[rr] += hs * ww;
            }
        }

#pragma unroll
    for (int off = 1; off < 16; off <<= 1)
#pragma unroll
        for (int rr = 0; rr < 4; ++rr)
            part[rr] += __shfl_xor(part[rr], off, 16);

    // ---- scatter from owning lanes (row = g*4 + rr) ----
    if (l15 == 0) {
        const float b2v = b2[0];
#pragma unroll
        for (int rr = 0; rr < 4; ++rr) {
            float sv = part[rr] + b2v;
            atomicAdd(&out[(long)nd[rr] * 3 + 0], sv * vx[rr]);
            atomicAdd(&out[(long)nd[rr] * 3 + 1], sv * vy[rr]);
            atomicAdd(&out[(long)nd[rr] * 3 + 2], sv * vz[rr]);
        }
    }
}

extern "C" void kernel_launch(void* const* d_in, const int* in_sizes, int n_in,
                              void* d_out, int out_size, void* d_ws, size_t ws_size,
                              hipStream_t stream) {
    const float* forces = (const float*)d_in[0];
    const float* V_st   = (const float*)d_in[1];
    const float* W1     = (const float*)d_in[2];
    const float* b1     = (const float*)d_in[3];
    const float* W2     = (const float*)d_in[4];
    const float* b2     = (const float*)d_in[5];
    const int*   idx    = (const int*)d_in[6];
    const int E = in_sizes[6];

    u16* W1F = (u16*)d_ws;  // 256*256*2 = 131072 B

    prep_kernel<<<D + 128, 256, 0, stream>>>(W1, W1F, (float*)d_out, out_size);
    const int grid = E / BM;
    head_kernel<<<grid, NT, 0, stream>>>(forces, V_st, W1F, b1, W2, b2, idx,
                                         (float*)d_out, E);
}

// Round 19
// 280.617 us; speedup vs baseline: 2.7725x; 1.5577x over previous
//
#include <hip/hip_runtime.h>
#include <hip/hip_bf16.h>

typedef __attribute__((ext_vector_type(8))) short short8;
typedef __attribute__((ext_vector_type(4))) float floatx4;
typedef unsigned short u16;

#define D 256
#define BM 64
#define NT 256

__device__ __forceinline__ short f2bf(float f) {
    return __builtin_bit_cast(short, __float2bfloat16(f));
}

// prep: blocks [0,256): W1 fp32 [k][n] -> W1F bf16 MFMA-fragment-major:
// W1F[((k0t*16+nt)*64+lane)*8+j] = W1[k0t*32+(lane>>4)*8+j][nt*16+(lane&15)]
//       blocks [256,384): zero d_out.
__global__ void prep_kernel(const float* __restrict__ W1, u16* __restrict__ W1F,
                            float* __restrict__ out, int outn) {
    const int b = blockIdx.x;
    if (b < D) {
        const int k = b, n = threadIdx.x;
        const int k0t = k >> 5, g = (k >> 3) & 3, j = k & 7;
        const int nt = n >> 4, l15 = n & 15;
        W1F[(long)((((k0t << 4) + nt) << 6) + (g << 4) + l15) * 8 + j] = (u16)f2bf(W1[k * D + n]);
    } else {
        int i = (b - D) * 256 + threadIdx.x;
        const int stride = (gridDim.x - D) * 256;
        for (; i < outn; i += stride) out[i] = 0.f;
    }
}

struct R8 { floatx4 f0, f1; };

// R11 base (64-edge tile, 4 waves, 32.5 KiB LDS, 4 blocks/CU, burst staging)
// with TALLER wave tiles: each wave owns ALL 64 rows x one 64-col quarter.
// B-traffic: 32 KB per wave per 64 rows = 2 KB/row -- HALF of R11's 4 KB/row
// (R17 showed 8 KB/row costs ~190us of L2 service; this halves R11's share).
// A-LDS reads double (32 KB/wave) but LDS is the cheap pipe.
__launch_bounds__(NT, 4)
__global__ void head_kernel(const float* __restrict__ forces,
                            const float* __restrict__ V_st,
                            const u16*   __restrict__ W1F,
                            const float* __restrict__ b1,
                            const float* __restrict__ W2,
                            const float* __restrict__ b2,
                            const int*   __restrict__ idx_t,
                            float* __restrict__ out,
                            int E) {
    // A frag f = k0t*4 + (row>>4); in-frag slot ((g<<4)|(row&15))*8 + j shorts
    __shared__ u16 Albs[32 * 512];    // 32 KiB
    __shared__ float s_red[4][BM];    // 1 KiB

    const int tid  = threadIdx.x;
    const int lane = tid & 63;
    const int wq   = tid >> 6;        // 0..3: col quarter owned by this wave
    const int l15  = lane & 15;
    const int g    = lane >> 4;       // 0..3

    const long row0 = (long)blockIdx.x * BM;   // E%64==0: no tail

    // ---- scatter-operand prefetch (in flight across the whole block) ----
    float vx = 0.f, vy = 0.f, vz = 0.f;
    int node = -1;
    if (tid < BM) {
        long e = row0 + tid;
        vx = V_st[e * 3 + 0]; vy = V_st[e * 3 + 1]; vz = V_st[e * 3 + 2];
        node = idx_t[e];
    }

    // ---- stage A: burst 16 loads (thread = arow=tid>>2, agg=tid&3) ----
    const int arow = tid >> 2;        // 0..63
    const int agg  = tid & 3;
    const float* abase = forces + (row0 + arow) * D + agg * 8;

    R8 r[8];
#pragma unroll
    for (int k0t = 0; k0t < 8; ++k0t) {
        r[k0t].f0 = *(const floatx4*)(abase + k0t * 32);
        r[k0t].f1 = *(const floatx4*)(abase + k0t * 32 + 4);
    }
    const int aslot = ((agg << 4) | (arow & 15)) * 8;
    const int art   = arow >> 4;
#pragma unroll
    for (int k0t = 0; k0t < 8; ++k0t) {
        short8 a;
#pragma unroll
        for (int j = 0; j < 4; ++j) { a[j] = f2bf(r[k0t].f0[j]); a[4 + j] = f2bf(r[k0t].f1[j]); }
        *(short8*)&Albs[(k0t * 4 + art) * 512 + aslot] = a;
    }
    __syncthreads();

    // ---- MFMA: wave tile 64 rows x 64 cols = 4 rt x 4 nc fragments ----
    floatx4 acc[4][4];
#pragma unroll
    for (int rt = 0; rt < 4; ++rt)
#pragma unroll
        for (int nc = 0; nc < 4; ++nc)
            acc[rt][nc] = (floatx4){0.f, 0.f, 0.f, 0.f};

#pragma unroll
    for (int k0t = 0; k0t < 8; ++k0t) {
        short8 bf[4], af[4];
#pragma unroll
        for (int nc = 0; nc < 4; ++nc)
            bf[nc] = *(const short8*)(W1F + (long)((k0t * 16 + wq * 4 + nc) * 64 + lane) * 8);
#pragma unroll
        for (int rt = 0; rt < 4; ++rt)
            af[rt] = *(const short8*)&Albs[(k0t * 4 + rt) * 512 + lane * 8];
#pragma unroll
        for (int rt = 0; rt < 4; ++rt)
#pragma unroll
            for (int nc = 0; nc < 4; ++nc)
                acc[rt][nc] = __builtin_amdgcn_mfma_f32_16x16x32_bf16(
                    af[rt], bf[nc], acc[rt][nc], 0, 0, 0);
    }

    // ---- epilogue: silu(z+b1) dot W2 over this wave's 64 cols ----
    float b1v[4], w2v[4];
#pragma unroll
    for (int nc = 0; nc < 4; ++nc) {
        int n = wq * 64 + nc * 16 + l15;
        b1v[nc] = b1[n];
        w2v[nc] = W2[n];
    }
    float part[4][4];  // [rt][rr]; C/D: col=lane&15, row=(lane>>4)*4+reg (m89)
#pragma unroll
    for (int rt = 0; rt < 4; ++rt)
#pragma unroll
        for (int rr = 0; rr < 4; ++rr) {
            float sv = 0.f;
#pragma unroll
            for (int nc = 0; nc < 4; ++nc) {
                float z = acc[rt][nc][rr] + b1v[nc];
                float h = z / (1.f + __expf(-z));
                sv += h * w2v[nc];
            }
            part[rt][rr] = sv;
        }

#pragma unroll
    for (int off = 1; off < 16; off <<= 1)
#pragma unroll
        for (int rt = 0; rt < 4; ++rt)
#pragma unroll
            for (int rr = 0; rr < 4; ++rr)
                part[rt][rr] += __shfl_xor(part[rt][rr], off, 16);

    if (l15 == 0) {
#pragma unroll
        for (int rt = 0; rt < 4; ++rt)
#pragma unroll
            for (int rr = 0; rr < 4; ++rr)
                s_red[wq][rt * 16 + g * 4 + rr] = part[rt][rr];
    }
    __syncthreads();

    // ---- scalar + scatter (operands already in registers) ----
    if (node >= 0) {
        float sv = s_red[0][tid] + s_red[1][tid] + s_red[2][tid] + s_red[3][tid] + b2[0];
        atomicAdd(&out[(long)node * 3 + 0], sv * vx);
        atomicAdd(&out[(long)node * 3 + 1], sv * vy);
        atomicAdd(&out[(long)node * 3 + 2], sv * vz);
    }
}

extern "C" void kernel_launch(void* const* d_in, const int* in_sizes, int n_in,
                              void* d_out, int out_size, void* d_ws, size_t ws_size,
                              hipStream_t stream) {
    const float* forces = (const float*)d_in[0];
    const float* V_st   = (const float*)d_in[1];
    const float* W1     = (const float*)d_in[2];
    const float* b1     = (const float*)d_in[3];
    const float* W2     = (const float*)d_in[4];
    const float* b2     = (const float*)d_in[5];
    const int*   idx    = (const int*)d_in[6];
    const int E = in_sizes[6];

    u16* W1F = (u16*)d_ws;  // 256*256*2 = 131072 B

    prep_kernel<<<D + 128, 256, 0, stream>>>(W1, W1F, (float*)d_out, out_size);
    const int grid = E / BM;
    head_kernel<<<grid, NT, 0, stream>>>(forces, V_st, W1F, b1, W2, b2, idx,
                                         (float*)d_out, E);
}